// Round 1
// baseline (936.226 us; speedup 1.0000x reference)
//
#include <hip/hip_runtime.h>
#include <stdint.h>

#define NCH 128

// ---------------- CSR construction ----------------

__global__ __launch_bounds__(256) void count_kernel(const int* __restrict__ dst,
                                                    int* __restrict__ counts, int E) {
    int i = blockIdx.x * blockDim.x + threadIdx.x;
    int stride = gridDim.x * blockDim.x;
    for (; i < E; i += stride) atomicAdd(&counts[dst[i]], 1);
}

__global__ __launch_bounds__(256) void dis_kernel(const int* __restrict__ counts,
                                                  float* __restrict__ dis, int n) {
    int i = blockIdx.x * blockDim.x + threadIdx.x;
    if (i < n) dis[i] = rsqrtf((float)(counts[i] + 1));   // +1 self loop
}

__global__ __launch_bounds__(1024) void scan1_kernel(const int* __restrict__ counts,
                                                     int* __restrict__ incl,
                                                     int* __restrict__ bsums, int n) {
    __shared__ int tmp[1024];
    int i = blockIdx.x * 1024 + threadIdx.x;
    int v = (i < n) ? counts[i] : 0;
    tmp[threadIdx.x] = v;
    __syncthreads();
    for (int off = 1; off < 1024; off <<= 1) {
        int t = (threadIdx.x >= off) ? tmp[threadIdx.x - off] : 0;
        __syncthreads();
        tmp[threadIdx.x] += t;
        __syncthreads();
    }
    if (i < n) incl[i] = tmp[threadIdx.x];
    if (threadIdx.x == 1023) bsums[blockIdx.x] = tmp[1023];
}

__global__ __launch_bounds__(128) void scan2_kernel(int* __restrict__ bsums, int nb) {
    __shared__ int tmp[128];
    int v = (threadIdx.x < nb) ? bsums[threadIdx.x] : 0;
    tmp[threadIdx.x] = v;
    __syncthreads();
    for (int off = 1; off < 128; off <<= 1) {
        int t = (threadIdx.x >= off) ? tmp[threadIdx.x - off] : 0;
        __syncthreads();
        tmp[threadIdx.x] += t;
        __syncthreads();
    }
    if (threadIdx.x < nb) bsums[threadIdx.x] = tmp[threadIdx.x] - v;  // exclusive
}

__global__ __launch_bounds__(256) void offsets_kernel(const int* __restrict__ incl,
                                                      const int* __restrict__ counts,
                                                      const int* __restrict__ bsums,
                                                      int* __restrict__ offsets,
                                                      int* __restrict__ cursor, int n) {
    int i = blockIdx.x * blockDim.x + threadIdx.x;
    if (i < n) {
        int e = incl[i] - counts[i] + bsums[i >> 10];
        offsets[i] = e;
        cursor[i] = e;
    }
}

__global__ __launch_bounds__(256) void fill_kernel(const int* __restrict__ src,
                                                   const int* __restrict__ dst,
                                                   int* __restrict__ cursor,
                                                   int* __restrict__ esrc, int E) {
    int i = blockIdx.x * blockDim.x + threadIdx.x;
    int stride = gridDim.x * blockDim.x;
    for (; i < E; i += stride) {
        int s = src[i];
        int d = dst[i];
        int pos = atomicAdd(&cursor[d], 1);
        esrc[pos] = s;
    }
}

// ---------------- GEMM: C[n,128] = A[n,128] @ W[128,128] ----------------
// block = 256 threads -> 32 rows x 128 cols; thread computes 4 rows x 4 cols.
// W read straight from global (64 KB, L1/L2-resident, broadcast across lanes).

__global__ __launch_bounds__(256) void gemm_kernel(const float* __restrict__ A,
                                                   const float* __restrict__ W,
                                                   float* __restrict__ C, int n) {
    int t = threadIdx.x;
    int rg = t >> 5;       // 0..7  -> 4-row group
    int cg = t & 31;       // 0..31 -> 4-col group
    int row0 = blockIdx.x * 32 + rg * 4;
    if (row0 >= n) return;
    const float* a0 = A + (size_t)row0 * NCH;

    float acc[4][4] = {{0.f}};
    for (int k = 0; k < NCH; k += 4) {
        float4 xv[4];
#pragma unroll
        for (int r = 0; r < 4; ++r)
            xv[r] = *(const float4*)(a0 + r * NCH + k);
#pragma unroll
        for (int kk = 0; kk < 4; ++kk) {
            float4 wv = *(const float4*)(W + (size_t)(k + kk) * NCH + cg * 4);
#pragma unroll
            for (int r = 0; r < 4; ++r) {
                float xr = ((const float*)&xv[r])[kk];
                acc[r][0] = fmaf(xr, wv.x, acc[r][0]);
                acc[r][1] = fmaf(xr, wv.y, acc[r][1]);
                acc[r][2] = fmaf(xr, wv.z, acc[r][2]);
                acc[r][3] = fmaf(xr, wv.w, acc[r][3]);
            }
        }
    }
#pragma unroll
    for (int r = 0; r < 4; ++r) {
        float4 o = make_float4(acc[r][0], acc[r][1], acc[r][2], acc[r][3]);
        *(float4*)(C + (size_t)(row0 + r) * NCH + cg * 4) = o;
    }
}

// ---------------- Aggregation: out[i] = sum_{e in CSR[i]} h[src]*dis[src]*dis[i]
//                  + h[i]*dis[i]^2 (self loop) + bias; optional relu.
// One wave per node, each lane holds 2 channels (float2).

__global__ __launch_bounds__(256) void agg_kernel(const float* __restrict__ h,
                                                  const float* __restrict__ dis,
                                                  const int* __restrict__ offsets,
                                                  const int* __restrict__ counts,
                                                  const int* __restrict__ esrc,
                                                  const float* __restrict__ bias,
                                                  float* __restrict__ out,
                                                  int n, int do_relu) {
    int gw = (blockIdx.x * blockDim.x + threadIdx.x) >> 6;  // global wave = node
    int lane = threadIdx.x & 63;
    if (gw >= n) return;
    int node = gw;

    float dn = dis[node];
    int o = offsets[node];
    int c = counts[node];

    const float2* hp = (const float2*)h;
    float2 hv = hp[(size_t)node * 64 + lane];
    float w0 = dn * dn;
    float ax = hv.x * w0, ay = hv.y * w0;

    for (int e = o; e < o + c; ++e) {
        int s = esrc[e];
        float w = dis[s] * dn;
        float2 v = hp[(size_t)s * 64 + lane];
        ax = fmaf(v.x, w, ax);
        ay = fmaf(v.y, w, ay);
    }

    float2 b = ((const float2*)bias)[lane];
    ax += b.x;
    ay += b.y;
    if (do_relu) { ax = fmaxf(ax, 0.f); ay = fmaxf(ay, 0.f); }
    float2 o2;
    o2.x = ax;
    o2.y = ay;
    ((float2*)out)[(size_t)node * 64 + lane] = o2;
}

// ---------------- launch ----------------

extern "C" void kernel_launch(void* const* d_in, const int* in_sizes, int n_in,
                              void* d_out, int out_size, void* d_ws, size_t ws_size,
                              hipStream_t stream) {
    const float* x  = (const float*)d_in[0];
    const int* edge = (const int*)d_in[2];
    const float* W1 = (const float*)d_in[5];
    const float* b1 = (const float*)d_in[6];
    const float* W2 = (const float*)d_in[7];
    const float* b2 = (const float*)d_in[8];

    int n = in_sizes[0] / NCH;
    int E = in_sizes[2] / 2;
    const int* srcp = edge;       // edge_index[0]
    const int* dstp = edge + E;   // edge_index[1]

    char* ws = (char*)d_ws;
    int*   counts  = (int*)ws;   ws += (size_t)n * 4;
    int*   incl    = (int*)ws;   ws += (size_t)n * 4;
    int*   offsets = (int*)ws;   ws += (size_t)n * 4;
    int*   cursor  = (int*)ws;   ws += (size_t)n * 4;
    float* dis     = (float*)ws; ws += (size_t)n * 4;
    int*   bsums   = (int*)ws;   ws += 1024;
    int*   esrc    = (int*)ws;   ws += (size_t)E * 4;
    uintptr_t p = ((uintptr_t)ws + 255) & ~(uintptr_t)255;
    float* h = (float*)p;        // n*128 floats = 51.2 MB
    float* out = (float*)d_out;

    hipMemsetAsync(counts, 0, (size_t)n * 4, stream);

    count_kernel<<<1024, 256, 0, stream>>>(dstp, counts, E);
    dis_kernel<<<(n + 255) / 256, 256, 0, stream>>>(counts, dis, n);

    int nb = (n + 1023) / 1024;   // 98 <= 128
    scan1_kernel<<<nb, 1024, 0, stream>>>(counts, incl, bsums, n);
    scan2_kernel<<<1, 128, 0, stream>>>(bsums, nb);
    offsets_kernel<<<(n + 255) / 256, 256, 0, stream>>>(incl, counts, bsums, offsets, cursor, n);
    fill_kernel<<<1024, 256, 0, stream>>>(srcp, dstp, cursor, esrc, E);

    int gemm_blocks = (n + 31) / 32;
    int agg_blocks  = (n + 3) / 4;   // 4 waves of 64 per block, 1 node per wave

    // layer 1: h = x @ W1 ; out = relu(agg(h) + b1)   (out == d_out used as temp)
    gemm_kernel<<<gemm_blocks, 256, 0, stream>>>(x, W1, h, n);
    agg_kernel<<<agg_blocks, 256, 0, stream>>>(h, dis, offsets, counts, esrc, b1, out, n, 1);
    // layer 2: h = out @ W2 ; out = agg(h) + b2
    gemm_kernel<<<gemm_blocks, 256, 0, stream>>>(out, W2, h, n);
    agg_kernel<<<agg_blocks, 256, 0, stream>>>(h, dis, offsets, counts, esrc, b2, out, n, 0);
}

// Round 2
// 683.778 us; speedup vs baseline: 1.3692x; 1.3692x over previous
//
#include <hip/hip_runtime.h>
#include <stdint.h>

#define NCH 128

// ---------------- CSR construction ----------------

__global__ __launch_bounds__(256) void count_kernel(const int* __restrict__ dst,
                                                    int* __restrict__ counts, int E) {
    int i = blockIdx.x * blockDim.x + threadIdx.x;
    int stride = gridDim.x * blockDim.x;
    for (; i < E; i += stride) atomicAdd(&counts[dst[i]], 1);
}

__global__ __launch_bounds__(256) void dis_kernel(const int* __restrict__ counts,
                                                  float* __restrict__ dis, int n) {
    int i = blockIdx.x * blockDim.x + threadIdx.x;
    if (i < n) dis[i] = rsqrtf((float)(counts[i] + 1));   // +1 self loop
}

__global__ __launch_bounds__(1024) void scan1_kernel(const int* __restrict__ counts,
                                                     int* __restrict__ incl,
                                                     int* __restrict__ bsums, int n) {
    __shared__ int tmp[1024];
    int i = blockIdx.x * 1024 + threadIdx.x;
    int v = (i < n) ? counts[i] : 0;
    tmp[threadIdx.x] = v;
    __syncthreads();
    for (int off = 1; off < 1024; off <<= 1) {
        int t = (threadIdx.x >= off) ? tmp[threadIdx.x - off] : 0;
        __syncthreads();
        tmp[threadIdx.x] += t;
        __syncthreads();
    }
    if (i < n) incl[i] = tmp[threadIdx.x];
    if (threadIdx.x == 1023) bsums[blockIdx.x] = tmp[1023];
}

__global__ __launch_bounds__(128) void scan2_kernel(int* __restrict__ bsums, int nb) {
    __shared__ int tmp[128];
    int v = (threadIdx.x < nb) ? bsums[threadIdx.x] : 0;
    tmp[threadIdx.x] = v;
    __syncthreads();
    for (int off = 1; off < 128; off <<= 1) {
        int t = (threadIdx.x >= off) ? tmp[threadIdx.x - off] : 0;
        __syncthreads();
        tmp[threadIdx.x] += t;
        __syncthreads();
    }
    if (threadIdx.x < nb) bsums[threadIdx.x] = tmp[threadIdx.x] - v;  // exclusive
}

__global__ __launch_bounds__(256) void offsets_kernel(const int* __restrict__ incl,
                                                      const int* __restrict__ counts,
                                                      const int* __restrict__ bsums,
                                                      int* __restrict__ offsets,
                                                      int* __restrict__ cursor, int n) {
    int i = blockIdx.x * blockDim.x + threadIdx.x;
    if (i < n) {
        int e = incl[i] - counts[i] + bsums[i >> 10];
        offsets[i] = e;
        cursor[i] = e;
    }
}

// fill: store per-edge meta (src, dis[src]) so agg's inner loop has no
// dependent scalar gathers.
__global__ __launch_bounds__(256) void fill_kernel(const int* __restrict__ src,
                                                   const int* __restrict__ dst,
                                                   const float* __restrict__ dis,
                                                   int* __restrict__ cursor,
                                                   int2* __restrict__ emeta, int E) {
    int i = blockIdx.x * blockDim.x + threadIdx.x;
    int stride = gridDim.x * blockDim.x;
    for (; i < E; i += stride) {
        int s = src[i];
        int d = dst[i];
        float w = dis[s];
        int pos = atomicAdd(&cursor[d], 1);
        emeta[pos] = make_int2(s, __float_as_int(w));
    }
}

// ---------------- GEMM: C[n,128] = A[n,128] @ W[128,128] ----------------
// 64x64 tile per block; W slice (128x64 = 32 KB) staged in LDS once.
// Thread computes 4 rows x 4 cols.

__global__ __launch_bounds__(256) void gemm_kernel(const float* __restrict__ A,
                                                   const float* __restrict__ W,
                                                   float* __restrict__ C, int n) {
    __shared__ float4 ws4[128 * 16];   // [k][c4], 32 KB
    int t = threadIdx.x;
    int nrb = (n + 63) >> 6;
    int rb = blockIdx.x % nrb;
    int cb = blockIdx.x / nrb;         // 0 or 1

    // stage W[:, cb*64 .. cb*64+63] into LDS
    for (int i = t; i < 128 * 16; i += 256) {
        int k = i >> 4, c4 = i & 15;
        ws4[i] = *(const float4*)(W + (size_t)k * NCH + cb * 64 + c4 * 4);
    }
    __syncthreads();

    int rg = t >> 4;       // 0..15 -> 4-row group
    int cg = t & 15;       // 0..15 -> 4-col group
    int row0 = rb * 64 + rg * 4;

    // clamp rows for loads (stores guarded) to avoid branches in hot loop
    int r0 = min(row0 + 0, n - 1);
    int r1 = min(row0 + 1, n - 1);
    int r2 = min(row0 + 2, n - 1);
    int r3 = min(row0 + 3, n - 1);
    const float* a0 = A + (size_t)r0 * NCH;
    const float* a1 = A + (size_t)r1 * NCH;
    const float* a2 = A + (size_t)r2 * NCH;
    const float* a3 = A + (size_t)r3 * NCH;

    float acc[4][4] = {{0.f}};
    for (int k = 0; k < NCH; k += 4) {
        float4 xv[4];
        xv[0] = *(const float4*)(a0 + k);
        xv[1] = *(const float4*)(a1 + k);
        xv[2] = *(const float4*)(a2 + k);
        xv[3] = *(const float4*)(a3 + k);
#pragma unroll
        for (int kk = 0; kk < 4; ++kk) {
            float4 wv = ws4[(k + kk) * 16 + cg];
#pragma unroll
            for (int r = 0; r < 4; ++r) {
                float xr = ((const float*)&xv[r])[kk];
                acc[r][0] = fmaf(xr, wv.x, acc[r][0]);
                acc[r][1] = fmaf(xr, wv.y, acc[r][1]);
                acc[r][2] = fmaf(xr, wv.z, acc[r][2]);
                acc[r][3] = fmaf(xr, wv.w, acc[r][3]);
            }
        }
    }
#pragma unroll
    for (int r = 0; r < 4; ++r) {
        if (row0 + r < n) {
            float4 o = make_float4(acc[r][0], acc[r][1], acc[r][2], acc[r][3]);
            *(float4*)(C + (size_t)(row0 + r) * NCH + cb * 64 + cg * 4) = o;
        }
    }
}

// ---------------- Aggregation ----------------
// One wave per node. Lane preloads one edge-meta; metas broadcast via shfl.
// 4 independent 512B row gathers in flight per wave.

__global__ __launch_bounds__(256) void agg_kernel(const float* __restrict__ h,
                                                  const float* __restrict__ dis,
                                                  const int* __restrict__ offsets,
                                                  const int* __restrict__ counts,
                                                  const int2* __restrict__ emeta,
                                                  const float* __restrict__ bias,
                                                  float* __restrict__ out,
                                                  int n, int do_relu) {
    int gw = (blockIdx.x * blockDim.x + threadIdx.x) >> 6;
    int lane = threadIdx.x & 63;
    if (gw >= n) return;
    int node = gw;

    float dn = dis[node];
    int o = offsets[node];
    int c = counts[node];

    const float2* hp = (const float2*)h;
    float2 hv = hp[(size_t)node * 64 + lane];
    float w0s = dn * dn;
    float ax = hv.x * w0s, ay = hv.y * w0s;

    // preload up to 64 edge metas (coalesced, one 8B load per lane)
    int2 m = (lane < c) ? emeta[o + lane] : make_int2(0, 0);
    int cc = min(c, 64);
    int j = 0;
    for (; j + 4 <= cc; j += 4) {
        int s0 = __shfl(m.x, j);     float w0 = __int_as_float(__shfl(m.y, j)) * dn;
        int s1 = __shfl(m.x, j + 1); float w1 = __int_as_float(__shfl(m.y, j + 1)) * dn;
        int s2 = __shfl(m.x, j + 2); float w2 = __int_as_float(__shfl(m.y, j + 2)) * dn;
        int s3 = __shfl(m.x, j + 3); float w3 = __int_as_float(__shfl(m.y, j + 3)) * dn;
        float2 v0 = hp[(size_t)s0 * 64 + lane];
        float2 v1 = hp[(size_t)s1 * 64 + lane];
        float2 v2 = hp[(size_t)s2 * 64 + lane];
        float2 v3 = hp[(size_t)s3 * 64 + lane];
        ax = fmaf(v0.x, w0, ax); ay = fmaf(v0.y, w0, ay);
        ax = fmaf(v1.x, w1, ax); ay = fmaf(v1.y, w1, ay);
        ax = fmaf(v2.x, w2, ax); ay = fmaf(v2.y, w2, ay);
        ax = fmaf(v3.x, w3, ax); ay = fmaf(v3.y, w3, ay);
    }
    for (; j < cc; ++j) {
        int s = __shfl(m.x, j);
        float w = __int_as_float(__shfl(m.y, j)) * dn;
        float2 v = hp[(size_t)s * 64 + lane];
        ax = fmaf(v.x, w, ax); ay = fmaf(v.y, w, ay);
    }
    // ultra-rare tail (degree > 64)
    for (int e = o + 64; e < o + c; ++e) {
        int2 me = emeta[e];
        float w = __int_as_float(me.y) * dn;
        float2 v = hp[(size_t)me.x * 64 + lane];
        ax = fmaf(v.x, w, ax); ay = fmaf(v.y, w, ay);
    }

    float2 b = ((const float2*)bias)[lane];
    ax += b.x;
    ay += b.y;
    if (do_relu) { ax = fmaxf(ax, 0.f); ay = fmaxf(ay, 0.f); }
    float2 o2; o2.x = ax; o2.y = ay;
    ((float2*)out)[(size_t)node * 64 + lane] = o2;
}

// ---------------- launch ----------------

extern "C" void kernel_launch(void* const* d_in, const int* in_sizes, int n_in,
                              void* d_out, int out_size, void* d_ws, size_t ws_size,
                              hipStream_t stream) {
    const float* x  = (const float*)d_in[0];
    const int* edge = (const int*)d_in[2];
    const float* W1 = (const float*)d_in[5];
    const float* b1 = (const float*)d_in[6];
    const float* W2 = (const float*)d_in[7];
    const float* b2 = (const float*)d_in[8];

    int n = in_sizes[0] / NCH;
    int E = in_sizes[2] / 2;
    const int* srcp = edge;       // edge_index[0]
    const int* dstp = edge + E;   // edge_index[1]

    char* ws = (char*)d_ws;
    int*   counts  = (int*)ws;   ws += (size_t)n * 4;
    int*   incl    = (int*)ws;   ws += (size_t)n * 4;
    int*   offsets = (int*)ws;   ws += (size_t)n * 4;
    int*   cursor  = (int*)ws;   ws += (size_t)n * 4;
    float* dis     = (float*)ws; ws += (size_t)n * 4;
    int*   bsums   = (int*)ws;   ws += 1024;
    uintptr_t pm = ((uintptr_t)ws + 255) & ~(uintptr_t)255;
    int2*  emeta   = (int2*)pm;  pm += (size_t)E * 8;
    uintptr_t p = (pm + 255) & ~(uintptr_t)255;
    float* h = (float*)p;        // n*128 floats = 51.2 MB
    float* out = (float*)d_out;

    hipMemsetAsync(counts, 0, (size_t)n * 4, stream);

    count_kernel<<<1024, 256, 0, stream>>>(dstp, counts, E);
    dis_kernel<<<(n + 255) / 256, 256, 0, stream>>>(counts, dis, n);

    int nb = (n + 1023) / 1024;   // 98 <= 128
    scan1_kernel<<<nb, 1024, 0, stream>>>(counts, incl, bsums, n);
    scan2_kernel<<<1, 128, 0, stream>>>(bsums, nb);
    offsets_kernel<<<(n + 255) / 256, 256, 0, stream>>>(incl, counts, bsums, offsets, cursor, n);
    fill_kernel<<<1024, 256, 0, stream>>>(srcp, dstp, dis, cursor, emeta, E);

    int nrb = (n + 63) / 64;
    int gemm_blocks = nrb * 2;       // 2 column-blocks of 64
    int agg_blocks  = (n + 3) / 4;   // 4 waves of 64 per block, 1 node per wave

    // layer 1: h = x @ W1 ; out = relu(agg(h) + b1)   (out == d_out used as temp)
    gemm_kernel<<<gemm_blocks, 256, 0, stream>>>(x, W1, h, n);
    agg_kernel<<<agg_blocks, 256, 0, stream>>>(h, dis, offsets, counts, emeta, b1, out, n, 1);
    // layer 2: h = out @ W2 ; out = agg(h) + b2
    gemm_kernel<<<gemm_blocks, 256, 0, stream>>>(out, W2, h, n);
    agg_kernel<<<agg_blocks, 256, 0, stream>>>(h, dis, offsets, counts, emeta, b2, out, n, 0);
}

// Round 3
// 571.527 us; speedup vs baseline: 1.6381x; 1.1964x over previous
//
#include <hip/hip_runtime.h>
#include <hip/hip_fp16.h>
#include <stdint.h>

#define NCH 128

// ---------------- CSR construction ----------------

__global__ __launch_bounds__(256) void count_kernel(const int* __restrict__ dst,
                                                    int* __restrict__ counts, int E) {
    int i = blockIdx.x * blockDim.x + threadIdx.x;
    if (i < E) atomicAdd(&counts[dst[i]], 1);
}

__global__ __launch_bounds__(256) void dis_kernel(const int* __restrict__ counts,
                                                  float* __restrict__ dis, int n) {
    int i = blockIdx.x * blockDim.x + threadIdx.x;
    if (i < n) dis[i] = rsqrtf((float)(counts[i] + 1));   // +1 self loop
}

__global__ __launch_bounds__(1024) void scan1_kernel(const int* __restrict__ counts,
                                                     int* __restrict__ incl,
                                                     int* __restrict__ bsums, int n) {
    __shared__ int tmp[1024];
    int i = blockIdx.x * 1024 + threadIdx.x;
    int v = (i < n) ? counts[i] : 0;
    tmp[threadIdx.x] = v;
    __syncthreads();
    for (int off = 1; off < 1024; off <<= 1) {
        int t = (threadIdx.x >= off) ? tmp[threadIdx.x - off] : 0;
        __syncthreads();
        tmp[threadIdx.x] += t;
        __syncthreads();
    }
    if (i < n) incl[i] = tmp[threadIdx.x];
    if (threadIdx.x == 1023) bsums[blockIdx.x] = tmp[1023];
}

__global__ __launch_bounds__(128) void scan2_kernel(int* __restrict__ bsums, int nb) {
    __shared__ int tmp[128];
    int v = (threadIdx.x < nb) ? bsums[threadIdx.x] : 0;
    tmp[threadIdx.x] = v;
    __syncthreads();
    for (int off = 1; off < 128; off <<= 1) {
        int t = (threadIdx.x >= off) ? tmp[threadIdx.x - off] : 0;
        __syncthreads();
        tmp[threadIdx.x] += t;
        __syncthreads();
    }
    if (threadIdx.x < nb) bsums[threadIdx.x] = tmp[threadIdx.x] - v;  // exclusive
}

__global__ __launch_bounds__(256) void offsets_kernel(const int* __restrict__ incl,
                                                      const int* __restrict__ counts,
                                                      const int* __restrict__ bsums,
                                                      int* __restrict__ offsets,
                                                      int* __restrict__ cursor, int n) {
    int i = blockIdx.x * blockDim.x + threadIdx.x;
    if (i < n) {
        int e = incl[i] - counts[i] + bsums[i >> 10];
        offsets[i] = e;
        cursor[i] = e;
    }
}

// fill: one thread per edge — max MLP on the atomic->scattered-store chain.
__global__ __launch_bounds__(256) void fill_kernel(const int* __restrict__ src,
                                                   const int* __restrict__ dst,
                                                   const float* __restrict__ dis,
                                                   int* __restrict__ cursor,
                                                   int2* __restrict__ emeta, int E) {
    int i = blockIdx.x * blockDim.x + threadIdx.x;
    if (i >= E) return;
    int s = src[i];
    int d = dst[i];
    float w = dis[s];
    int pos = atomicAdd(&cursor[d], 1);
    emeta[pos] = make_int2(s, __float_as_int(w));
}

// ---------------- GEMM: C[n,128](fp16) = A[n,128](fp32) @ W[128,128] ----------------
// 64x64 tile per block; W slice (128x64 = 32 KB) staged in LDS once.
// Thread computes 4 rows x 4 cols; output rounded to fp16.

__global__ __launch_bounds__(256) void gemm_kernel(const float* __restrict__ A,
                                                   const float* __restrict__ W,
                                                   __half* __restrict__ C, int n) {
    __shared__ float4 ws4[128 * 16];   // [k][c4], 32 KB
    int t = threadIdx.x;
    int nrb = (n + 63) >> 6;
    int rb = blockIdx.x % nrb;
    int cb = blockIdx.x / nrb;         // 0 or 1

    for (int i = t; i < 128 * 16; i += 256) {
        int k = i >> 4, c4 = i & 15;
        ws4[i] = *(const float4*)(W + (size_t)k * NCH + cb * 64 + c4 * 4);
    }
    __syncthreads();

    int rg = t >> 4;       // 0..15 -> 4-row group
    int cg = t & 15;       // 0..15 -> 4-col group
    int row0 = rb * 64 + rg * 4;

    int r0 = min(row0 + 0, n - 1);
    int r1 = min(row0 + 1, n - 1);
    int r2 = min(row0 + 2, n - 1);
    int r3 = min(row0 + 3, n - 1);
    const float* a0 = A + (size_t)r0 * NCH;
    const float* a1 = A + (size_t)r1 * NCH;
    const float* a2 = A + (size_t)r2 * NCH;
    const float* a3 = A + (size_t)r3 * NCH;

    float acc[4][4] = {{0.f}};
    for (int k = 0; k < NCH; k += 4) {
        float4 xv[4];
        xv[0] = *(const float4*)(a0 + k);
        xv[1] = *(const float4*)(a1 + k);
        xv[2] = *(const float4*)(a2 + k);
        xv[3] = *(const float4*)(a3 + k);
#pragma unroll
        for (int kk = 0; kk < 4; ++kk) {
            float4 wv = ws4[(k + kk) * 16 + cg];
#pragma unroll
            for (int r = 0; r < 4; ++r) {
                float xr = ((const float*)&xv[r])[kk];
                acc[r][0] = fmaf(xr, wv.x, acc[r][0]);
                acc[r][1] = fmaf(xr, wv.y, acc[r][1]);
                acc[r][2] = fmaf(xr, wv.z, acc[r][2]);
                acc[r][3] = fmaf(xr, wv.w, acc[r][3]);
            }
        }
    }
#pragma unroll
    for (int r = 0; r < 4; ++r) {
        if (row0 + r < n) {
            __half2 p0 = __floats2half2_rn(acc[r][0], acc[r][1]);
            __half2 p1 = __floats2half2_rn(acc[r][2], acc[r][3]);
            uint2 o;
            o.x = *(unsigned int*)&p0;
            o.y = *(unsigned int*)&p1;
            *(uint2*)(C + (size_t)(row0 + r) * NCH + cb * 64 + cg * 4) = o;
        }
    }
}

// ---------------- Aggregation ----------------
// One wave per node; h is fp16 (256B per gathered row). Edge metas preloaded
// (one coalesced 8B load/lane) and broadcast via shfl; unroll-4 gathers.

__global__ __launch_bounds__(256) void agg_kernel(const __half2* __restrict__ hp,
                                                  const float* __restrict__ dis,
                                                  const int* __restrict__ offsets,
                                                  const int* __restrict__ counts,
                                                  const int2* __restrict__ emeta,
                                                  const float* __restrict__ bias,
                                                  float* __restrict__ out,
                                                  int n, int do_relu) {
    int gw = (blockIdx.x * blockDim.x + threadIdx.x) >> 6;
    int lane = threadIdx.x & 63;
    if (gw >= n) return;
    int node = gw;

    float dn = dis[node];
    int o = offsets[node];
    int c = counts[node];

    float2 hv = __half22float2(hp[(size_t)node * 64 + lane]);
    float w0s = dn * dn;
    float ax = hv.x * w0s, ay = hv.y * w0s;

    int2 m = (lane < c) ? emeta[o + lane] : make_int2(0, 0);
    int cc = min(c, 64);
    int j = 0;
    for (; j + 4 <= cc; j += 4) {
        int s0 = __shfl(m.x, j);     float w0 = __int_as_float(__shfl(m.y, j)) * dn;
        int s1 = __shfl(m.x, j + 1); float w1 = __int_as_float(__shfl(m.y, j + 1)) * dn;
        int s2 = __shfl(m.x, j + 2); float w2 = __int_as_float(__shfl(m.y, j + 2)) * dn;
        int s3 = __shfl(m.x, j + 3); float w3 = __int_as_float(__shfl(m.y, j + 3)) * dn;
        float2 v0 = __half22float2(hp[(size_t)s0 * 64 + lane]);
        float2 v1 = __half22float2(hp[(size_t)s1 * 64 + lane]);
        float2 v2 = __half22float2(hp[(size_t)s2 * 64 + lane]);
        float2 v3 = __half22float2(hp[(size_t)s3 * 64 + lane]);
        ax = fmaf(v0.x, w0, ax); ay = fmaf(v0.y, w0, ay);
        ax = fmaf(v1.x, w1, ax); ay = fmaf(v1.y, w1, ay);
        ax = fmaf(v2.x, w2, ax); ay = fmaf(v2.y, w2, ay);
        ax = fmaf(v3.x, w3, ax); ay = fmaf(v3.y, w3, ay);
    }
    for (; j < cc; ++j) {
        int s = __shfl(m.x, j);
        float w = __int_as_float(__shfl(m.y, j)) * dn;
        float2 v = __half22float2(hp[(size_t)s * 64 + lane]);
        ax = fmaf(v.x, w, ax); ay = fmaf(v.y, w, ay);
    }
    for (int e = o + 64; e < o + c; ++e) {   // rare degree>64 tail
        int2 me = emeta[e];
        float w = __int_as_float(me.y) * dn;
        float2 v = __half22float2(hp[(size_t)me.x * 64 + lane]);
        ax = fmaf(v.x, w, ax); ay = fmaf(v.y, w, ay);
    }

    float2 b = ((const float2*)bias)[lane];
    ax += b.x;
    ay += b.y;
    if (do_relu) { ax = fmaxf(ax, 0.f); ay = fmaxf(ay, 0.f); }
    float2 o2; o2.x = ax; o2.y = ay;
    ((float2*)out)[(size_t)node * 64 + lane] = o2;
}

// ---------------- launch ----------------

extern "C" void kernel_launch(void* const* d_in, const int* in_sizes, int n_in,
                              void* d_out, int out_size, void* d_ws, size_t ws_size,
                              hipStream_t stream) {
    const float* x  = (const float*)d_in[0];
    const int* edge = (const int*)d_in[2];
    const float* W1 = (const float*)d_in[5];
    const float* b1 = (const float*)d_in[6];
    const float* W2 = (const float*)d_in[7];
    const float* b2 = (const float*)d_in[8];

    int n = in_sizes[0] / NCH;
    int E = in_sizes[2] / 2;
    const int* srcp = edge;       // edge_index[0]
    const int* dstp = edge + E;   // edge_index[1]

    char* ws = (char*)d_ws;
    int*   counts  = (int*)ws;   ws += (size_t)n * 4;
    int*   incl    = (int*)ws;   ws += (size_t)n * 4;
    int*   offsets = (int*)ws;   ws += (size_t)n * 4;
    int*   cursor  = (int*)ws;   ws += (size_t)n * 4;
    float* dis     = (float*)ws; ws += (size_t)n * 4;
    int*   bsums   = (int*)ws;   ws += 1024;
    uintptr_t pm = ((uintptr_t)ws + 255) & ~(uintptr_t)255;
    int2*  emeta   = (int2*)pm;  pm += (size_t)E * 8;
    uintptr_t p = (pm + 255) & ~(uintptr_t)255;
    __half* h = (__half*)p;      // n*128 fp16 = 25.6 MB
    float* out = (float*)d_out;

    hipMemsetAsync(counts, 0, (size_t)n * 4, stream);

    count_kernel<<<(E + 255) / 256, 256, 0, stream>>>(dstp, counts, E);
    dis_kernel<<<(n + 255) / 256, 256, 0, stream>>>(counts, dis, n);

    int nb = (n + 1023) / 1024;   // 98 <= 128
    scan1_kernel<<<nb, 1024, 0, stream>>>(counts, incl, bsums, n);
    scan2_kernel<<<1, 128, 0, stream>>>(bsums, nb);
    offsets_kernel<<<(n + 255) / 256, 256, 0, stream>>>(incl, counts, bsums, offsets, cursor, n);
    fill_kernel<<<(E + 255) / 256, 256, 0, stream>>>(srcp, dstp, dis, cursor, emeta, E);

    int nrb = (n + 63) / 64;
    int gemm_blocks = nrb * 2;       // 2 column-blocks of 64
    int agg_blocks  = (n + 3) / 4;   // 4 waves of 64 per block, 1 node per wave

    // layer 1: h = fp16(x @ W1) ; out = relu(agg(h) + b1)
    gemm_kernel<<<gemm_blocks, 256, 0, stream>>>(x, W1, h, n);
    agg_kernel<<<agg_blocks, 256, 0, stream>>>((const __half2*)h, dis, offsets, counts, emeta, b1, out, n, 1);
    // layer 2: h = fp16(out @ W2) ; out = agg(h) + b2
    gemm_kernel<<<gemm_blocks, 256, 0, stream>>>(out, W2, h, n);
    agg_kernel<<<agg_blocks, 256, 0, stream>>>((const __half2*)h, dis, offsets, counts, emeta, b2, out, n, 0);
}

// Round 4
// 487.691 us; speedup vs baseline: 1.9197x; 1.1719x over previous
//
#include <hip/hip_runtime.h>
#include <hip/hip_fp16.h>
#include <stdint.h>

#define NCH 128

using half8  = __attribute__((ext_vector_type(8))) _Float16;
using floatx4 = __attribute__((ext_vector_type(4))) float;

// ---------------- CSR construction ----------------

__global__ __launch_bounds__(256) void count_kernel(const int* __restrict__ dst,
                                                    int* __restrict__ counts, int E) {
    int i = blockIdx.x * blockDim.x + threadIdx.x;
    if (i < E) atomicAdd(&counts[dst[i]], 1);
}

__global__ __launch_bounds__(1024) void scan1_kernel(const int* __restrict__ counts,
                                                     int* __restrict__ incl,
                                                     int* __restrict__ bsums, int n) {
    __shared__ int tmp[1024];
    int i = blockIdx.x * 1024 + threadIdx.x;
    int v = (i < n) ? counts[i] : 0;
    tmp[threadIdx.x] = v;
    __syncthreads();
    for (int off = 1; off < 1024; off <<= 1) {
        int t = (threadIdx.x >= off) ? tmp[threadIdx.x - off] : 0;
        __syncthreads();
        tmp[threadIdx.x] += t;
        __syncthreads();
    }
    if (i < n) incl[i] = tmp[threadIdx.x];
    if (threadIdx.x == 1023) bsums[blockIdx.x] = tmp[1023];
}

__global__ __launch_bounds__(128) void scan2_kernel(int* __restrict__ bsums, int nb) {
    __shared__ int tmp[128];
    int v = (threadIdx.x < nb) ? bsums[threadIdx.x] : 0;
    tmp[threadIdx.x] = v;
    __syncthreads();
    for (int off = 1; off < 128; off <<= 1) {
        int t = (threadIdx.x >= off) ? tmp[threadIdx.x - off] : 0;
        __syncthreads();
        tmp[threadIdx.x] += t;
        __syncthreads();
    }
    if (threadIdx.x < nb) bsums[threadIdx.x] = tmp[threadIdx.x] - v;  // exclusive
}

__global__ __launch_bounds__(256) void offsets_kernel(const int* __restrict__ incl,
                                                      const int* __restrict__ counts,
                                                      const int* __restrict__ bsums,
                                                      int* __restrict__ offsets,
                                                      int* __restrict__ cursor, int n) {
    int i = blockIdx.x * blockDim.x + threadIdx.x;
    if (i < n) {
        int e = incl[i] - counts[i] + bsums[i >> 10];
        offsets[i] = e;
        cursor[i] = e;
    }
}

// fill: 4-byte packed meta (src | (deg+1)<<17). src < 2^17, deg+1 < 2^15.
__global__ __launch_bounds__(256) void fill_kernel(const int* __restrict__ src,
                                                   const int* __restrict__ dst,
                                                   const int* __restrict__ counts,
                                                   int* __restrict__ cursor,
                                                   unsigned int* __restrict__ emeta, int E) {
    int i = blockIdx.x * blockDim.x + threadIdx.x;
    if (i >= E) return;
    int s = src[i];
    int d = dst[i];
    unsigned int degp1 = (unsigned int)counts[s] + 1u;
    int pos = atomicAdd(&cursor[d], 1);
    emeta[pos] = (unsigned int)s | (degp1 << 17);
}

// ---------------- W pre-swizzle: W[128][128] fp32 -> B-fragment-order fp16 ----
// Fragment cell c (0..2047): pair p=c>>6 (kc=p>>3, ct=p&7), lane=c&63.
// Cell holds 8 fp16: B[k][n] with n=ct*16+(lane&15), k=kc*32+(lane>>4)*8+j.

__global__ __launch_bounds__(256) void wprep_kernel(const float* __restrict__ W1,
                                                    const float* __restrict__ W2,
                                                    __half* __restrict__ Wt1,
                                                    __half* __restrict__ Wt2) {
    int b = blockIdx.x;                       // 0..15
    const float* W = (b < 8) ? W1 : W2;
    __half* Wt     = (b < 8) ? Wt1 : Wt2;
    int c = (b & 7) * 256 + threadIdx.x;      // 0..2047
    int p = c >> 6, lane = c & 63;
    int kc = p >> 3, ct = p & 7;
    int nn = ct * 16 + (lane & 15);
    int kbase = kc * 32 + (lane >> 4) * 8;
    half8 hv;
#pragma unroll
    for (int j = 0; j < 8; ++j)
        hv[j] = (_Float16)W[(size_t)(kbase + j) * NCH + nn];
    *(half8*)(Wt + (size_t)c * 8) = hv;
}

// ---------------- MFMA GEMM: C[n,128](fp16) = A[n,128](fp32) @ W ----------------
// 256 threads = 4 waves; wave computes 32 rows x 128 cols via 16x16x32 f16 MFMA.
// Wt (fragment-order fp16, 32KB) staged to LDS; epilogue reuses LDS for
// coalesced fp16 row stores.
// Layouts (m89/m120-verified): A[m=lane&15][k=(lane>>4)*8+j],
// B[k=(lane>>4)*8+j][n=lane&15], D col=lane&15 row=(lane>>4)*4+reg.

__global__ __launch_bounds__(256) void gemm_kernel(const float* __restrict__ A,
                                                   const __half* __restrict__ Wt,
                                                   __half* __restrict__ C, int n) {
    __shared__ float4 lds[2048];   // 32 KB
    int t = threadIdx.x;
    for (int i = t; i < 2048; i += 256) lds[i] = ((const float4*)Wt)[i];
    __syncthreads();

    int wave = t >> 6, lane = t & 63;
    int q = lane >> 4, m16 = lane & 15;
    int rowbase = blockIdx.x * 128 + wave * 32;

    floatx4 acc[2][8];
#pragma unroll
    for (int g = 0; g < 2; ++g)
#pragma unroll
        for (int ct = 0; ct < 8; ++ct) {
            acc[g][ct][0] = 0.f; acc[g][ct][1] = 0.f;
            acc[g][ct][2] = 0.f; acc[g][ct][3] = 0.f;
        }

    const half8* bfr = (const half8*)lds;

    int ra0 = min(rowbase + m16, n - 1);
    int ra1 = min(rowbase + 16 + m16, n - 1);
    const float* pa0 = A + (size_t)ra0 * NCH;
    const float* pa1 = A + (size_t)ra1 * NCH;

#pragma unroll
    for (int kc = 0; kc < 4; ++kc) {
        int ko = kc * 32 + q * 8;
        float4 f0 = *(const float4*)(pa0 + ko);
        float4 f1 = *(const float4*)(pa0 + ko + 4);
        float4 g0 = *(const float4*)(pa1 + ko);
        float4 g1 = *(const float4*)(pa1 + ko + 4);
        half8 a0, a1;
        a0[0] = (_Float16)f0.x; a0[1] = (_Float16)f0.y;
        a0[2] = (_Float16)f0.z; a0[3] = (_Float16)f0.w;
        a0[4] = (_Float16)f1.x; a0[5] = (_Float16)f1.y;
        a0[6] = (_Float16)f1.z; a0[7] = (_Float16)f1.w;
        a1[0] = (_Float16)g0.x; a1[1] = (_Float16)g0.y;
        a1[2] = (_Float16)g0.z; a1[3] = (_Float16)g0.w;
        a1[4] = (_Float16)g1.x; a1[5] = (_Float16)g1.y;
        a1[6] = (_Float16)g1.z; a1[7] = (_Float16)g1.w;
#pragma unroll
        for (int ct = 0; ct < 8; ++ct) {
            half8 b = bfr[(kc * 8 + ct) * 64 + lane];
            acc[0][ct] = __builtin_amdgcn_mfma_f32_16x16x32_f16(a0, b, acc[0][ct], 0, 0, 0);
            acc[1][ct] = __builtin_amdgcn_mfma_f32_16x16x32_f16(a1, b, acc[1][ct], 0, 0, 0);
        }
    }

    __syncthreads();   // all waves done with Wt fragments; reuse LDS as scratch
    float* scr = (float*)lds + wave * 2048;   // 16 rows x 128 f32 per wave
#pragma unroll
    for (int g = 0; g < 2; ++g) {
#pragma unroll
        for (int reg = 0; reg < 4; ++reg)
#pragma unroll
            for (int ct = 0; ct < 8; ++ct)
                scr[(q * 4 + reg) * NCH + ct * 16 + m16] = acc[g][ct][reg];
        // within-wave LDS RAW: compiler inserts lgkmcnt wait; no barrier needed
        int row0 = rowbase + g * 16;
#pragma unroll
        for (int r = 0; r < 16; ++r) {
            int row = row0 + r;
            if (row < n) {
                float2 v = *(float2*)(scr + r * NCH + lane * 2);
                __half2 hh = __floats2half2_rn(v.x, v.y);
                *(unsigned int*)(C + (size_t)row * NCH + lane * 2) = *(unsigned int*)&hh;
            }
        }
    }
}

// ---------------- Aggregation ----------------
// One wave per node; h fp16 (256B rows). 4B metas preloaded (coalesced) and
// broadcast via shfl; 4 independent row gathers in flight.

__global__ __launch_bounds__(256) void agg_kernel(const __half2* __restrict__ hp,
                                                  const int* __restrict__ offsets,
                                                  const int* __restrict__ counts,
                                                  const unsigned int* __restrict__ emeta,
                                                  const float* __restrict__ bias,
                                                  float* __restrict__ out,
                                                  int n, int do_relu) {
    int gw = (blockIdx.x * blockDim.x + threadIdx.x) >> 6;
    int lane = threadIdx.x & 63;
    if (gw >= n) return;
    int node = gw;

    int o = offsets[node];
    int c = counts[node];
    float dn = rsqrtf((float)(c + 1));

    float2 hv = __half22float2(hp[(size_t)node * 64 + lane]);
    float w0s = dn * dn;
    float ax = hv.x * w0s, ay = hv.y * w0s;

    unsigned int m = (lane < c) ? emeta[o + lane] : 0u;
    int cc = min(c, 64);
    int j = 0;
    for (; j + 4 <= cc; j += 4) {
        unsigned int p0 = (unsigned int)__shfl((int)m, j);
        unsigned int p1 = (unsigned int)__shfl((int)m, j + 1);
        unsigned int p2 = (unsigned int)__shfl((int)m, j + 2);
        unsigned int p3 = (unsigned int)__shfl((int)m, j + 3);
        int s0 = p0 & 0x1FFFF; float w0 = rsqrtf((float)(p0 >> 17)) * dn;
        int s1 = p1 & 0x1FFFF; float w1 = rsqrtf((float)(p1 >> 17)) * dn;
        int s2 = p2 & 0x1FFFF; float w2 = rsqrtf((float)(p2 >> 17)) * dn;
        int s3 = p3 & 0x1FFFF; float w3 = rsqrtf((float)(p3 >> 17)) * dn;
        float2 v0 = __half22float2(hp[(size_t)s0 * 64 + lane]);
        float2 v1 = __half22float2(hp[(size_t)s1 * 64 + lane]);
        float2 v2 = __half22float2(hp[(size_t)s2 * 64 + lane]);
        float2 v3 = __half22float2(hp[(size_t)s3 * 64 + lane]);
        ax = fmaf(v0.x, w0, ax); ay = fmaf(v0.y, w0, ay);
        ax = fmaf(v1.x, w1, ax); ay = fmaf(v1.y, w1, ay);
        ax = fmaf(v2.x, w2, ax); ay = fmaf(v2.y, w2, ay);
        ax = fmaf(v3.x, w3, ax); ay = fmaf(v3.y, w3, ay);
    }
    for (; j < cc; ++j) {
        unsigned int p = (unsigned int)__shfl((int)m, j);
        int s = p & 0x1FFFF; float w = rsqrtf((float)(p >> 17)) * dn;
        float2 v = __half22float2(hp[(size_t)s * 64 + lane]);
        ax = fmaf(v.x, w, ax); ay = fmaf(v.y, w, ay);
    }
    for (int e = o + 64; e < o + c; ++e) {   // rare degree>64 tail
        unsigned int p = emeta[e];
        int s = p & 0x1FFFF; float w = rsqrtf((float)(p >> 17)) * dn;
        float2 v = __half22float2(hp[(size_t)s * 64 + lane]);
        ax = fmaf(v.x, w, ax); ay = fmaf(v.y, w, ay);
    }

    float2 b = ((const float2*)bias)[lane];
    ax += b.x;
    ay += b.y;
    if (do_relu) { ax = fmaxf(ax, 0.f); ay = fmaxf(ay, 0.f); }
    float2 o2; o2.x = ax; o2.y = ay;
    ((float2*)out)[(size_t)node * 64 + lane] = o2;
}

// ---------------- launch ----------------

extern "C" void kernel_launch(void* const* d_in, const int* in_sizes, int n_in,
                              void* d_out, int out_size, void* d_ws, size_t ws_size,
                              hipStream_t stream) {
    const float* x  = (const float*)d_in[0];
    const int* edge = (const int*)d_in[2];
    const float* W1 = (const float*)d_in[5];
    const float* b1 = (const float*)d_in[6];
    const float* W2 = (const float*)d_in[7];
    const float* b2 = (const float*)d_in[8];

    int n = in_sizes[0] / NCH;
    int E = in_sizes[2] / 2;
    const int* srcp = edge;       // edge_index[0]
    const int* dstp = edge + E;   // edge_index[1]

    char* ws = (char*)d_ws;
    int*   counts  = (int*)ws;   ws += (size_t)n * 4;
    int*   incl    = (int*)ws;   ws += (size_t)n * 4;
    int*   offsets = (int*)ws;   ws += (size_t)n * 4;
    int*   cursor  = (int*)ws;   ws += (size_t)n * 4;
    int*   bsums   = (int*)ws;   ws += 1024;
    uintptr_t pw = ((uintptr_t)ws + 255) & ~(uintptr_t)255;
    __half* Wt1 = (__half*)pw;   pw += 2048 * 16;
    __half* Wt2 = (__half*)pw;   pw += 2048 * 16;
    unsigned int* emeta = (unsigned int*)pw; pw += (size_t)E * 4;
    uintptr_t p = (pw + 255) & ~(uintptr_t)255;
    __half* h = (__half*)p;      // n*128 fp16 = 25.6 MB
    float* out = (float*)d_out;

    hipMemsetAsync(counts, 0, (size_t)n * 4, stream);

    wprep_kernel<<<16, 256, 0, stream>>>(W1, W2, Wt1, Wt2);
    count_kernel<<<(E + 255) / 256, 256, 0, stream>>>(dstp, counts, E);

    int nb = (n + 1023) / 1024;   // 98 <= 128
    scan1_kernel<<<nb, 1024, 0, stream>>>(counts, incl, bsums, n);
    scan2_kernel<<<1, 128, 0, stream>>>(bsums, nb);
    offsets_kernel<<<(n + 255) / 256, 256, 0, stream>>>(incl, counts, bsums, offsets, cursor, n);
    fill_kernel<<<(E + 255) / 256, 256, 0, stream>>>(srcp, dstp, counts, cursor, emeta, E);

    int gemm_blocks = (n + 127) / 128;
    int agg_blocks  = (n + 3) / 4;   // 4 waves of 64 per block, 1 node per wave

    // layer 1: h = fp16(x @ W1) ; out = relu(agg(h) + b1)
    gemm_kernel<<<gemm_blocks, 256, 0, stream>>>(x, Wt1, h, n);
    agg_kernel<<<agg_blocks, 256, 0, stream>>>((const __half2*)h, offsets, counts, emeta, b1, out, n, 1);
    // layer 2: h = fp16(out @ W2) ; out = agg(h) + b2
    gemm_kernel<<<gemm_blocks, 256, 0, stream>>>(out, Wt2, h, n);
    agg_kernel<<<agg_blocks, 256, 0, stream>>>((const __half2*)h, offsets, counts, emeta, b2, out, n, 0);
}